// Round 8
// baseline (67.503 us; speedup 1.0000x reference)
//
#include <hip/hip_runtime.h>

// Problem constants: B=2, L=32, C=8, H=W=64
#define BB 2
#define LL 32
#define CC 8
#define HH 64
#define WW 64
#define HWL 4096

typedef _Float16 h2 __attribute__((ext_vector_type(2)));

#if defined(__has_builtin)
#if __has_builtin(__builtin_amdgcn_fdot2)
#define HAVE_FDOT2 1
#endif
#endif

__device__ __forceinline__ float fdot2f(uint32_t a, h2 b, float c) {
    union { uint32_t u; h2 h; } ua;
    ua.u = a;
#ifdef HAVE_FDOT2
    return __builtin_amdgcn_fdot2(ua.h, b, c, false);
#else
    return c + (float)ua.h.x * (float)b.x + (float)ua.h.y * (float)b.y;
#endif
}

__device__ __forceinline__ h2 f2h2(float lo, float hi) {
    h2 r;
    r.x = (_Float16)lo;
    r.y = (_Float16)hi;
    return r;
}

__device__ __forceinline__ uint32_t pkh2(float lo, float hi) {
    union { h2 h; uint32_t u; } v;
    v.h = f2h2(lo, hi);
    return v.u;
}

// ---------------------------------------------------------------------------
// Kernel 1: cumsum of flows along L, STANDARD layout (b, l, 2, h, w).
// (Round-5-proven; per-k loads in the main kernel are lane-coalesced.)
// ---------------------------------------------------------------------------
__global__ __launch_bounds__(256) void cumsum_kernel(
    const float* __restrict__ flows, float* __restrict__ cum) {
    int idx = blockIdx.x * blockDim.x + threadIdx.x;  // over B*2*H*W = 32768
    if (idx >= BB * 2 * HWL) return;
    int pix  = idx & (HWL - 1);
    int rest = idx >> 12;  // b*2 + comp
    int comp = rest & 1;
    int b    = rest >> 1;
    size_t base = ((size_t)(b * LL) * 2 + comp) * HWL + pix;
    float acc = 0.0f;
    for (int l = 0; l < LL; ++l) {
        acc += flows[base + (size_t)l * 2 * HWL];
        cum[base + (size_t)l * 2 * HWL] = acc;
    }
}

// ---------------------------------------------------------------------------
// Kernel 2: repack images to 2-channel fp16 per-x records (parity-dup, the
// round-5-proven idiom, split into 4 channel-group planes).
// Plane p = (b*LL+l)*4 + cg, cg in [0,4): 64 rows x 64 recs x 8B = 32KB.
// Rec (y,x) = uint2: word0 = (img[2cg][y][x],   img[2cg][y][x+1]),
//                    word1 = (img[2cg+1][y][x], img[2cg+1][y][x+1]),
// with x+1 == 64 -> 0 pad. One ALIGNED 8B load covers both x-corners.
// ---------------------------------------------------------------------------
__global__ __launch_bounds__(256) void repack2_kernel(
    const float* __restrict__ img, uint32_t* __restrict__ planes) {
    int idx = blockIdx.x * blockDim.x + threadIdx.x;  // over 2*32*64*32
    if (idx >= BB * LL * HH * 32) return;
    int rec = idx & 31;        // x-pair base: x = 2*rec, 2*rec+1
    int y   = (idx >> 5) & 63;
    int bl  = idx >> 11;       // b*32 + l
    const float* ip = img + (size_t)bl * CC * HWL + y * WW + 2 * rec;
    bool last = (rec == 31);
    float a0[8], a1[8], bx[8];
#pragma unroll
    for (int c = 0; c < 8; ++c) {
        float2 A = *reinterpret_cast<const float2*>(ip + (size_t)c * HWL);
        a0[c] = A.x;
        a1[c] = A.y;
        bx[c] = last ? 0.0f : ip[(size_t)c * HWL + 2];
    }
#pragma unroll
    for (int cg = 0; cg < 4; ++cg) {
        // recs x=2*rec (even) and x=2*rec+1 (odd), written as one 16B store.
        uint4 w;
        w.x = pkh2(a0[2 * cg], a1[2 * cg]);
        w.y = pkh2(a0[2 * cg + 1], a1[2 * cg + 1]);
        w.z = pkh2(a1[2 * cg], bx[2 * cg]);
        w.w = pkh2(a1[2 * cg + 1], bx[2 * cg + 1]);
        *reinterpret_cast<uint4*>(planes +
                                  ((size_t)(bl * 4 + cg) * 4096 +
                                   (size_t)(y * 64 + 2 * rec)) * 2) = w;
    }
}

// ---------------------------------------------------------------------------
// Bilinear sample of a 2-channel fp16 record plane: one aligned uint2 load
// per row (covers both x corners); x0=-1 handled by weight shuffle (r5
// idiom). Grid math bit-identical to rounds 3-5. No out-of-plane reads.
// ---------------------------------------------------------------------------
__device__ __forceinline__ void sample2(const uint2* __restrict__ recs,
                                        float gx, float gy, float ckx,
                                        float cky, float ctx, float cty,
                                        float& acc0, float& acc1) {
    float g0 = gx + (ctx - ckx);
    float g1 = gy + (cty - cky);
    float a = g0 + 1.0f;
    float h = a * 0.5f;
    float rem = (h - floorf(h)) * 2.0f;        // remainder(g0+1, 2), exact
    float ix = fmaf(rem, 32.0f, -0.5f);
    float iy = fmaf(g1 + 1.0f, 32.0f, -0.5f);
    float x0f = floorf(ix), y0f = floorf(iy);
    float wx1 = ix - x0f, wy1 = iy - y0f;
    float wx0 = 1.0f - wx1, wy0 = 1.0f - wy1;
    int x0 = (int)x0f, y0 = (int)y0f;  // x0 in [-1,63] after wrap
    bool vx0 = x0 >= 0;
    bool vx1 = x0 < WW - 1;
    bool vy0 = (y0 >= 0) & (y0 < HH);
    bool vy1 = (y0 >= -1) & (y0 < HH - 1);
    float w00 = (vx0 && vy0) ? wx0 * wy0 : 0.0f;
    float w10 = (vx1 && vy0) ? wx1 * wy0 : 0.0f;
    float w01 = (vx0 && vy1) ? wx0 * wy1 : 0.0f;
    float w11 = (vx1 && vy1) ? wx1 * wy1 : 0.0f;
    int xa = max(x0, 0);  // x0=-1 -> rec 0 holds (px0,px1); v10 in slot 0
    bool lo1 = x0 < 0;
    float wA0 = lo1 ? w10 : w00, wB0 = lo1 ? 0.0f : w10;
    float wA1 = lo1 ? w11 : w01, wB1 = lo1 ? 0.0f : w11;
    int y0c = min(max(y0, 0), HH - 1), y1c = min(max(y0 + 1, 0), HH - 1);
    uint2 q0 = recs[y0c * 64 + xa];
    uint2 q1 = recs[y1c * 64 + xa];
    h2 h0 = f2h2(wA0, wB0);
    h2 h1 = f2h2(wA1, wB1);
    acc0 = fdot2f(q0.x, h0, acc0);
    acc1 = fdot2f(q0.y, h0, acc1);
    acc0 = fdot2f(q1.x, h1, acc0);
    acc1 = fdot2f(q1.y, h1, acc1);
}

// ---------------------------------------------------------------------------
// Kernel 3: thread = (cg, b, tl, y, x), cg in [0,4); handles t_lo = tl and
// t_hi = 31-tl (33 samples/thread, uniform work). cg outputs disjoint ->
// direct stores, no partial buffer. Grid = 2048 blocks = 8 blocks/CU.
// ---------------------------------------------------------------------------
__global__ __launch_bounds__(256) void warp_pscan_v8(
    const float* __restrict__ cum, const uint32_t* __restrict__ planes,
    float* __restrict__ out) {
    int idx = blockIdx.x * 256 + threadIdx.x;  // over 4*2*16*4096 = 524288
    if (idx >= 4 * BB * (LL / 2) * HWL) return;
    int x  = idx & (WW - 1);
    int y  = (idx >> 6) & (HH - 1);
    int tl = (idx >> 12) & 15;
    int b  = (idx >> 16) & 1;
    int cg = (idx >> 17) & 3;
    int t_lo = tl, t_hi = (LL - 1) - tl;
    int pix = y * WW + x;

    float gx = -1.0f + (float)(2 * x + 1) * (1.0f / WW);
    float gy = -1.0f + (float)(2 * y + 1) * (1.0f / HH);

    const float* cumb = cum + (size_t)b * LL * 2 * HWL + pix;
    float ctxlo = cumb[(size_t)(2 * t_lo) * HWL];
    float ctylo = cumb[(size_t)(2 * t_lo + 1) * HWL];
    float ctxhi = cumb[(size_t)(2 * t_hi) * HWL];
    float ctyhi = cumb[(size_t)(2 * t_hi + 1) * HWL];

    float a0l = 0.0f, a1l = 0.0f, a0h = 0.0f, a1h = 0.0f;

    const uint2* plb =
        reinterpret_cast<const uint2*>(planes) + (size_t)(b * LL * 4 + cg) * 4096;

#pragma unroll 2
    for (int k = 0; k <= t_hi; ++k) {
        float ckx = cumb[(size_t)(2 * k) * HWL];
        float cky = cumb[(size_t)(2 * k + 1) * HWL];
        const uint2* recs = plb + (size_t)k * 4 * 4096;
        sample2(recs, gx, gy, ckx, cky, ctxhi, ctyhi, a0h, a1h);
        if (k <= t_lo)  // block-uniform branch (tl is per-block)
            sample2(recs, gx, gy, ckx, cky, ctxlo, ctylo, a0l, a1l);
    }

    int c0 = cg * 2;
    float* ol = out + ((size_t)(b * LL + t_lo) * CC + c0) * HWL + pix;
    ol[0]   = a0l;
    ol[HWL] = a1l;
    float* oh = out + ((size_t)(b * LL + t_hi) * CC + c0) * HWL + pix;
    oh[0]   = a0h;
    oh[HWL] = a1h;
}

// ---------------------------------------------------------------------------
// Fallback (ws too small): fp32 scalar path, original layouts (r5-proven).
// ---------------------------------------------------------------------------
__global__ __launch_bounds__(256) void warp_pscan_fb(
    const float* __restrict__ cum, const float* __restrict__ images,
    float* __restrict__ out) {
    int idx = blockIdx.x * blockDim.x + threadIdx.x;
    if (idx >= BB * LL * HWL) return;
    int x  = idx & (WW - 1);
    int y  = (idx >> 6) & (HH - 1);
    int tl = (idx >> 12) & (LL - 1);
    int b  = idx >> 17;
    int t = (tl < 16) ? tl : (47 - tl);
    int pix = y * WW + x;
    float gx = -1.0f + (float)(2 * x + 1) * (1.0f / WW);
    float gy = -1.0f + (float)(2 * y + 1) * (1.0f / HH);
    const float* cumb = cum + (size_t)b * LL * 2 * HWL + pix;
    float ctx = cumb[(size_t)(2 * t) * HWL];
    float cty = cumb[(size_t)(2 * t + 1) * HWL];
    float acc[CC];
#pragma unroll
    for (int c = 0; c < CC; ++c) acc[c] = 0.0f;
    const float* imgb = images + (size_t)b * LL * CC * HWL;
    for (int k = 0; k <= t; ++k) {
        float dx = ctx - cumb[(size_t)(2 * k) * HWL];
        float dy = cty - cumb[(size_t)(2 * k + 1) * HWL];
        float g0 = gx + dx, g1 = gy + dy;
        float a = g0 + 1.0f, h = a * 0.5f;
        float rem = (h - floorf(h)) * 2.0f;
        float ix = fmaf(rem, 32.0f, -0.5f);
        float iy = fmaf(g1 + 1.0f, 32.0f, -0.5f);
        float x0f = floorf(ix), y0f = floorf(iy);
        float wx1 = ix - x0f, wy1 = iy - y0f;
        float wx0 = 1.0f - wx1, wy0 = 1.0f - wy1;
        int x0 = (int)x0f, y0 = (int)y0f;
        bool vx0 = x0 >= 0, vx1 = x0 < WW - 1;
        bool vy0 = (y0 >= 0) & (y0 < HH), vy1 = (y0 >= -1) & (y0 < HH - 1);
        int x0c = max(x0, 0), x1c = min(x0 + 1, WW - 1);
        int y0c = min(max(y0, 0), HH - 1), y1c = min(max(y0 + 1, 0), HH - 1);
        float w00 = (vx0 && vy0) ? wx0 * wy0 : 0.0f;
        float w10 = (vx1 && vy0) ? wx1 * wy0 : 0.0f;
        float w01 = (vx0 && vy1) ? wx0 * wy1 : 0.0f;
        float w11 = (vx1 && vy1) ? wx1 * wy1 : 0.0f;
        int o00 = y0c * WW + x0c, o10 = y0c * WW + x1c;
        int o01 = y1c * WW + x0c, o11 = y1c * WW + x1c;
        const float* ip = imgb + (size_t)k * CC * HWL;
#pragma unroll
        for (int c = 0; c < CC; ++c) {
            const float* ic = ip + (size_t)c * HWL;
            acc[c] += w00 * ic[o00] + w10 * ic[o10] + w01 * ic[o01] +
                      w11 * ic[o11];
        }
    }
    float* op = out + ((size_t)(b * LL + t) * CC) * HWL + pix;
#pragma unroll
    for (int c = 0; c < CC; ++c) op[(size_t)c * HWL] = acc[c];
}

extern "C" void kernel_launch(void* const* d_in, const int* in_sizes, int n_in,
                              void* d_out, int out_size, void* d_ws,
                              size_t ws_size, hipStream_t stream) {
    const float* flows  = (const float*)d_in[0];
    const float* images = (const float*)d_in[1];
    float* out = (float*)d_out;

    const size_t cum_bytes   = (size_t)BB * LL * 2 * HWL * sizeof(float);  // 2 MiB
    const size_t plane_bytes = (size_t)BB * LL * 4 * 4096 * 8;             // 8 MiB
    float* cum       = (float*)d_ws;
    uint32_t* planes = (uint32_t*)((char*)d_ws + cum_bytes);
    bool full = (ws_size >= cum_bytes + plane_bytes);

    int n1 = BB * 2 * HWL;
    cumsum_kernel<<<(n1 + 255) / 256, 256, 0, stream>>>(flows, cum);

    if (full) {
        int n2 = BB * LL * HH * 32;  // 131072
        repack2_kernel<<<(n2 + 255) / 256, 256, 0, stream>>>(images, planes);
        int n3 = 4 * BB * (LL / 2) * HWL;  // 524288
        warp_pscan_v8<<<n3 / 256, 256, 0, stream>>>(cum, planes, out);
    } else {
        int n3 = BB * LL * HWL;
        warp_pscan_fb<<<(n3 + 255) / 256, 256, 0, stream>>>(cum, images, out);
    }
}

// Round 10
// 63.338 us; speedup vs baseline: 1.0658x; 1.0658x over previous
//
#include <hip/hip_runtime.h>

// Problem constants: B=2, L=32, C=8, H=W=64
#define BB 2
#define LL 32
#define CC 8
#define HH 64
#define WW 64
#define HWL 4096

typedef _Float16 h2 __attribute__((ext_vector_type(2)));

#if defined(__has_builtin)
#if __has_builtin(__builtin_amdgcn_fdot2)
#define HAVE_FDOT2 1
#endif
#endif

__device__ __forceinline__ float fdot2f(uint32_t a, h2 b, float c) {
    union { uint32_t u; h2 h; } ua;
    ua.u = a;
#ifdef HAVE_FDOT2
    return __builtin_amdgcn_fdot2(ua.h, b, c, false);
#else
    return c + (float)ua.h.x * (float)b.x + (float)ua.h.y * (float)b.y;
#endif
}

__device__ __forceinline__ h2 f2h2(float lo, float hi) {
    h2 r;
    r.x = (_Float16)lo;
    r.y = (_Float16)hi;
    return r;
}

__device__ __forceinline__ uint32_t pkh2(float lo, float hi) {
    union { h2 h; uint32_t u; } v;
    v.h = f2h2(lo, hi);
    return v.u;
}

// ---------------------------------------------------------------------------
// Fused prep kernel.
// Blocks [0,64): flow cumsum over B*2*H*W = 2*2*4096 = 16384 threads
//   (NOTE: 64 blocks, NOT 128 — rounds 6/7/9 crashed from exactly this:
//   a stale "=32768" comment became CUM_BLOCKS=128 with no guard, and
//   threads 16384+ read flows[] up to 4x past the end -> page fault).
// Blocks [64, 576): repack images to 2-channel fp16 parity-dup records
//   (r8-proven layout), 131072 threads.
// ---------------------------------------------------------------------------
#define CUM_BLOCKS 64

__global__ __launch_bounds__(256) void prep_kernel(
    const float* __restrict__ flows, const float* __restrict__ img,
    float* __restrict__ cum, uint32_t* __restrict__ planes) {
    int bid = blockIdx.x;
    if (bid < CUM_BLOCKS) {
        int idx  = bid * 256 + threadIdx.x;  // over B*2*H*W = 16384
        if (idx >= BB * 2 * HWL) return;     // defensive (grid is exact)
        int pix  = idx & (HWL - 1);
        int rest = idx >> 12;  // b*2 + comp, in [0,4)
        int comp = rest & 1;
        int b    = rest >> 1;
        size_t base = ((size_t)(b * LL) * 2 + comp) * HWL + pix;
        float v[LL];
#pragma unroll
        for (int l = 0; l < LL; ++l) v[l] = flows[base + (size_t)l * 2 * HWL];
        float acc = 0.0f;
#pragma unroll
        for (int l = 0; l < LL; ++l) {
            acc += v[l];
            cum[base + (size_t)l * 2 * HWL] = acc;
        }
    } else {
        int idx = (bid - CUM_BLOCKS) * 256 + threadIdx.x;  // over 2*32*64*32
        if (idx >= BB * LL * HH * 32) return;              // defensive
        int rec = idx & 31;        // x-pair base: x = 2*rec, 2*rec+1
        int y   = (idx >> 5) & 63;
        int bl  = idx >> 11;       // b*32 + l, in [0,64)
        const float* ip = img + (size_t)bl * CC * HWL + y * WW + 2 * rec;
        bool last = (rec == 31);
        float a0[8], a1[8], bx[8];
#pragma unroll
        for (int c = 0; c < 8; ++c) {
            float2 A = *reinterpret_cast<const float2*>(ip + (size_t)c * HWL);
            a0[c] = A.x;
            a1[c] = A.y;
            bx[c] = last ? 0.0f : ip[(size_t)c * HWL + 2];
        }
#pragma unroll
        for (int cg = 0; cg < 4; ++cg) {
            uint4 w;  // recs x=2*rec (even) and x=2*rec+1 (odd), one 16B store
            w.x = pkh2(a0[2 * cg], a1[2 * cg]);
            w.y = pkh2(a0[2 * cg + 1], a1[2 * cg + 1]);
            w.z = pkh2(a1[2 * cg], bx[2 * cg]);
            w.w = pkh2(a1[2 * cg + 1], bx[2 * cg + 1]);
            *reinterpret_cast<uint4*>(planes +
                                      ((size_t)(bl * 4 + cg) * 4096 +
                                       (size_t)(y * 64 + 2 * rec)) * 2) = w;
        }
    }
}

// ---------------------------------------------------------------------------
// Bilinear sample of a 2-channel fp16 record plane (r8-proven): one aligned
// uint2 load per row covers both x corners; x0=-1 via weight shuffle.
// Grid math bit-identical to rounds 3-8.
// ---------------------------------------------------------------------------
__device__ __forceinline__ void sample2(const uint2* __restrict__ recs,
                                        float gx, float gy, float ckx,
                                        float cky, float ctx, float cty,
                                        float& acc0, float& acc1) {
    float g0 = gx + (ctx - ckx);
    float g1 = gy + (cty - cky);
    float a = g0 + 1.0f;
    float h = a * 0.5f;
    float rem = (h - floorf(h)) * 2.0f;        // remainder(g0+1, 2), exact
    float ix = fmaf(rem, 32.0f, -0.5f);
    float iy = fmaf(g1 + 1.0f, 32.0f, -0.5f);
    float x0f = floorf(ix), y0f = floorf(iy);
    float wx1 = ix - x0f, wy1 = iy - y0f;
    float wx0 = 1.0f - wx1, wy0 = 1.0f - wy1;
    int x0 = (int)x0f, y0 = (int)y0f;  // x0 in [-1,63] after wrap
    bool vx0 = x0 >= 0;
    bool vx1 = x0 < WW - 1;
    bool vy0 = (y0 >= 0) & (y0 < HH);
    bool vy1 = (y0 >= -1) & (y0 < HH - 1);
    float w00 = (vx0 && vy0) ? wx0 * wy0 : 0.0f;
    float w10 = (vx1 && vy0) ? wx1 * wy0 : 0.0f;
    float w01 = (vx0 && vy1) ? wx0 * wy1 : 0.0f;
    float w11 = (vx1 && vy1) ? wx1 * wy1 : 0.0f;
    int xa = max(x0, 0);  // x0=-1 -> rec 0 holds (px0,px1); v10 in slot 0
    bool lo1 = x0 < 0;
    float wA0 = lo1 ? w10 : w00, wB0 = lo1 ? 0.0f : w10;
    float wA1 = lo1 ? w11 : w01, wB1 = lo1 ? 0.0f : w11;
    int y0c = min(max(y0, 0), HH - 1), y1c = min(max(y0 + 1, 0), HH - 1);
    uint2 q0 = recs[y0c * 64 + xa];
    uint2 q1 = recs[y1c * 64 + xa];
    h2 h0 = f2h2(wA0, wB0);
    h2 h1 = f2h2(wA1, wB1);
    acc0 = fdot2f(q0.x, h0, acc0);
    acc1 = fdot2f(q0.y, h0, acc1);
    acc0 = fdot2f(q1.x, h1, acc0);
    acc1 = fdot2f(q1.y, h1, acc1);
}

// ---------------------------------------------------------------------------
// Main kernel: thread = (cg, b, tl, y, x), cg in [0,4); handles t_lo = tl
// and t_hi = 31-tl. k-loop in chunks of 8: 16 cum loads issued together up
// front, then 8 unrolled sample steps — decorrelates waitcnt stalls.
// __launch_bounds__(256, 8): 8 waves/SIMD -> VGPR <= 64, 8 blocks/CU.
// ---------------------------------------------------------------------------
__global__ __launch_bounds__(256, 8) void warp_pscan_v10(
    const float* __restrict__ cum, const uint32_t* __restrict__ planes,
    float* __restrict__ out) {
    int idx = blockIdx.x * 256 + threadIdx.x;  // over 4*2*16*4096 = 524288
    if (idx >= 4 * BB * (LL / 2) * HWL) return;  // defensive (grid is exact)
    int x  = idx & (WW - 1);
    int y  = (idx >> 6) & (HH - 1);
    int tl = (idx >> 12) & 15;
    int b  = (idx >> 16) & 1;
    int cg = (idx >> 17) & 3;
    int t_lo = tl, t_hi = (LL - 1) - tl;
    int pix = y * WW + x;

    float gx = -1.0f + (float)(2 * x + 1) * (1.0f / WW);
    float gy = -1.0f + (float)(2 * y + 1) * (1.0f / HH);

    const float* cumb = cum + (size_t)b * LL * 2 * HWL + pix;
    float ctxlo = cumb[(size_t)(2 * t_lo) * HWL];
    float ctylo = cumb[(size_t)(2 * t_lo + 1) * HWL];
    float ctxhi = cumb[(size_t)(2 * t_hi) * HWL];
    float ctyhi = cumb[(size_t)(2 * t_hi + 1) * HWL];

    float a0l = 0.0f, a1l = 0.0f, a0h = 0.0f, a1h = 0.0f;

    const uint2* plb =
        reinterpret_cast<const uint2*>(planes) + (size_t)(b * LL * 4 + cg) * 4096;

    for (int kc = 0; kc <= t_hi; kc += 8) {
        // Batch-load this chunk's cum values (kc+j <= 31 always in-bounds).
        float cx[8], cy[8];
#pragma unroll
        for (int j = 0; j < 8; ++j) {
            cx[j] = cumb[(size_t)(2 * (kc + j)) * HWL];
            cy[j] = cumb[(size_t)(2 * (kc + j) + 1) * HWL];
        }
#pragma unroll
        for (int j = 0; j < 8; ++j) {
            int k = kc + j;
            if (k <= t_hi) {
                const uint2* recs = plb + (size_t)k * 4 * 4096;
                sample2(recs, gx, gy, cx[j], cy[j], ctxhi, ctyhi, a0h, a1h);
                if (k <= t_lo)
                    sample2(recs, gx, gy, cx[j], cy[j], ctxlo, ctylo, a0l, a1l);
            }
        }
    }

    int c0 = cg * 2;
    float* ol = out + ((size_t)(b * LL + t_lo) * CC + c0) * HWL + pix;
    ol[0]   = a0l;
    ol[HWL] = a1l;
    float* oh = out + ((size_t)(b * LL + t_hi) * CC + c0) * HWL + pix;
    oh[0]   = a0h;
    oh[HWL] = a1h;
}

// ---------------------------------------------------------------------------
// Fallback (ws too small): fp32 scalar path, original layouts (r5-proven).
// ---------------------------------------------------------------------------
__global__ __launch_bounds__(256) void warp_pscan_fb(
    const float* __restrict__ cum, const float* __restrict__ images,
    float* __restrict__ out) {
    int idx = blockIdx.x * blockDim.x + threadIdx.x;
    if (idx >= BB * LL * HWL) return;
    int x  = idx & (WW - 1);
    int y  = (idx >> 6) & (HH - 1);
    int tl = (idx >> 12) & (LL - 1);
    int b  = idx >> 17;
    int t = (tl < 16) ? tl : (47 - tl);
    int pix = y * WW + x;
    float gx = -1.0f + (float)(2 * x + 1) * (1.0f / WW);
    float gy = -1.0f + (float)(2 * y + 1) * (1.0f / HH);
    const float* cumb = cum + (size_t)b * LL * 2 * HWL + pix;
    float ctx = cumb[(size_t)(2 * t) * HWL];
    float cty = cumb[(size_t)(2 * t + 1) * HWL];
    float acc[CC];
#pragma unroll
    for (int c = 0; c < CC; ++c) acc[c] = 0.0f;
    const float* imgb = images + (size_t)b * LL * CC * HWL;
    for (int k = 0; k <= t; ++k) {
        float dx = ctx - cumb[(size_t)(2 * k) * HWL];
        float dy = cty - cumb[(size_t)(2 * k + 1) * HWL];
        float g0 = gx + dx, g1 = gy + dy;
        float a = g0 + 1.0f, h = a * 0.5f;
        float rem = (h - floorf(h)) * 2.0f;
        float ix = fmaf(rem, 32.0f, -0.5f);
        float iy = fmaf(g1 + 1.0f, 32.0f, -0.5f);
        float x0f = floorf(ix), y0f = floorf(iy);
        float wx1 = ix - x0f, wy1 = iy - y0f;
        float wx0 = 1.0f - wx1, wy0 = 1.0f - wy1;
        int x0 = (int)x0f, y0 = (int)y0f;
        bool vx0 = x0 >= 0, vx1 = x0 < WW - 1;
        bool vy0 = (y0 >= 0) & (y0 < HH), vy1 = (y0 >= -1) & (y0 < HH - 1);
        int x0c = max(x0, 0), x1c = min(x0 + 1, WW - 1);
        int y0c = min(max(y0, 0), HH - 1), y1c = min(max(y0 + 1, 0), HH - 1);
        float w00 = (vx0 && vy0) ? wx0 * wy0 : 0.0f;
        float w10 = (vx1 && vy0) ? wx1 * wy0 : 0.0f;
        float w01 = (vx0 && vy1) ? wx0 * wy1 : 0.0f;
        float w11 = (vx1 && vy1) ? wx1 * wy1 : 0.0f;
        int o00 = y0c * WW + x0c, o10 = y0c * WW + x1c;
        int o01 = y1c * WW + x0c, o11 = y1c * WW + x1c;
        const float* ip = imgb + (size_t)k * CC * HWL;
#pragma unroll
        for (int c = 0; c < CC; ++c) {
            const float* ic = ip + (size_t)c * HWL;
            acc[c] += w00 * ic[o00] + w10 * ic[o10] + w01 * ic[o01] +
                      w11 * ic[o11];
        }
    }
    float* op = out + ((size_t)(b * LL + t) * CC) * HWL + pix;
#pragma unroll
    for (int c = 0; c < CC; ++c) op[(size_t)c * HWL] = acc[c];
}

extern "C" void kernel_launch(void* const* d_in, const int* in_sizes, int n_in,
                              void* d_out, int out_size, void* d_ws,
                              size_t ws_size, hipStream_t stream) {
    const float* flows  = (const float*)d_in[0];
    const float* images = (const float*)d_in[1];
    float* out = (float*)d_out;

    const size_t cum_bytes   = (size_t)BB * LL * 2 * HWL * sizeof(float);  // 2 MiB
    const size_t plane_bytes = (size_t)BB * LL * 4 * 4096 * 8;             // 8 MiB
    float* cum       = (float*)d_ws;
    uint32_t* planes = (uint32_t*)((char*)d_ws + cum_bytes);
    bool full = (ws_size >= cum_bytes + plane_bytes);

    if (full) {
        int nprep = CUM_BLOCKS + (BB * LL * HH * 32) / 256;  // 64 + 512 = 576
        prep_kernel<<<nprep, 256, 0, stream>>>(flows, images, cum, planes);
        int n3 = 4 * BB * (LL / 2) * HWL;  // 524288
        warp_pscan_v10<<<n3 / 256, 256, 0, stream>>>(cum, planes, out);
    } else {
        prep_kernel<<<CUM_BLOCKS, 256, 0, stream>>>(flows, images, cum,
                                                    planes);
        int n3 = BB * LL * HWL;
        warp_pscan_fb<<<(n3 + 255) / 256, 256, 0, stream>>>(cum, images, out);
    }
}

// Round 11
// 61.996 us; speedup vs baseline: 1.0888x; 1.0216x over previous
//
#include <hip/hip_runtime.h>

// Problem constants: B=2, L=32, C=8, H=W=64
#define BB 2
#define LL 32
#define CC 8
#define HH 64
#define WW 64
#define HWL 4096

typedef _Float16 h2 __attribute__((ext_vector_type(2)));

#if defined(__has_builtin)
#if __has_builtin(__builtin_amdgcn_fdot2)
#define HAVE_FDOT2 1
#endif
#endif

__device__ __forceinline__ float fdot2f(uint32_t a, h2 b, float c) {
    union { uint32_t u; h2 h; } ua;
    ua.u = a;
#ifdef HAVE_FDOT2
    return __builtin_amdgcn_fdot2(ua.h, b, c, false);
#else
    return c + (float)ua.h.x * (float)b.x + (float)ua.h.y * (float)b.y;
#endif
}

__device__ __forceinline__ h2 f2h2(float lo, float hi) {
    h2 r;
    r.x = (_Float16)lo;
    r.y = (_Float16)hi;
    return r;
}

__device__ __forceinline__ uint32_t pkh2(float lo, float hi) {
    union { h2 h; uint32_t u; } v;
    v.h = f2h2(lo, hi);
    return v.u;
}

// ---------------------------------------------------------------------------
// Fused prep kernel (r10-proven, CUM_BLOCKS=64 with guards).
// Blocks [0,64): flow cumsum over B*2*H*W = 16384 threads.
// Blocks [64,576): repack to 2-channel fp16 parity-dup records.
// ---------------------------------------------------------------------------
#define CUM_BLOCKS 64

__global__ __launch_bounds__(256) void prep_kernel(
    const float* __restrict__ flows, const float* __restrict__ img,
    float* __restrict__ cum, uint32_t* __restrict__ planes) {
    int bid = blockIdx.x;
    if (bid < CUM_BLOCKS) {
        int idx  = bid * 256 + threadIdx.x;
        if (idx >= BB * 2 * HWL) return;
        int pix  = idx & (HWL - 1);
        int rest = idx >> 12;  // b*2 + comp, in [0,4)
        int comp = rest & 1;
        int b    = rest >> 1;
        size_t base = ((size_t)(b * LL) * 2 + comp) * HWL + pix;
        float v[LL];
#pragma unroll
        for (int l = 0; l < LL; ++l) v[l] = flows[base + (size_t)l * 2 * HWL];
        float acc = 0.0f;
#pragma unroll
        for (int l = 0; l < LL; ++l) {
            acc += v[l];
            cum[base + (size_t)l * 2 * HWL] = acc;
        }
    } else {
        int idx = (bid - CUM_BLOCKS) * 256 + threadIdx.x;
        if (idx >= BB * LL * HH * 32) return;
        int rec = idx & 31;
        int y   = (idx >> 5) & 63;
        int bl  = idx >> 11;
        const float* ip = img + (size_t)bl * CC * HWL + y * WW + 2 * rec;
        bool last = (rec == 31);
        float a0[8], a1[8], bx[8];
#pragma unroll
        for (int c = 0; c < 8; ++c) {
            float2 A = *reinterpret_cast<const float2*>(ip + (size_t)c * HWL);
            a0[c] = A.x;
            a1[c] = A.y;
            bx[c] = last ? 0.0f : ip[(size_t)c * HWL + 2];
        }
#pragma unroll
        for (int cg = 0; cg < 4; ++cg) {
            uint4 w;
            w.x = pkh2(a0[2 * cg], a1[2 * cg]);
            w.y = pkh2(a0[2 * cg + 1], a1[2 * cg + 1]);
            w.z = pkh2(a1[2 * cg], bx[2 * cg]);
            w.w = pkh2(a1[2 * cg + 1], bx[2 * cg + 1]);
            *reinterpret_cast<uint4*>(planes +
                                      ((size_t)(bl * 4 + cg) * 4096 +
                                       (size_t)(y * 64 + 2 * rec)) * 2) = w;
        }
    }
}

// ---------------------------------------------------------------------------
// prep_s: grid math + weights + record offsets for one sample.
// ix formula bit-equal to rounds 3-10: rem = a - 2*floor(a/2) is exact, so
// fma(a,32, fma(floor(a/2),-64,-0.5)) == fma(rem,32,-0.5) bitwise.
// Weights packed to h2 immediately (halves live registers).
// ---------------------------------------------------------------------------
__device__ __forceinline__ void prep_s(float axv, float ayv, float ckx,
                                       float cky, int& off0, int& off1,
                                       h2& hw0, h2& hw1) {
    float aa = axv - ckx;                 // == g0 + 1 (±1ulp reassoc)
    float hh = aa * 0.5f;
    float fh = floorf(hh);
    float tt = fmaf(fh, -64.0f, -0.5f);   // exact: fh in {-1,0,1}
    float ix = fmaf(aa, 32.0f, tt);       // in [-0.5, 63.5)
    float ay = ayv - cky;                 // == g1 + 1
    float iy = fmaf(ay, 32.0f, -0.5f);
    float x0f = floorf(ix), y0f = floorf(iy);
    float wx1 = ix - x0f, wy1 = iy - y0f;
    float wx0 = 1.0f - wx1, wy0 = 1.0f - wy1;
    int x0 = (int)x0f, y0 = (int)y0f;     // x0 in [-1,63]
    bool vx0 = x0 >= 0;
    bool vx1 = x0 < WW - 1;
    bool vy0 = (y0 >= 0) & (y0 < HH);
    bool vy1 = (y0 >= -1) & (y0 < HH - 1);
    float w00 = (vx0 && vy0) ? wx0 * wy0 : 0.0f;
    float w10 = (vx1 && vy0) ? wx1 * wy0 : 0.0f;
    float w01 = (vx0 && vy1) ? wx0 * wy1 : 0.0f;
    float w11 = (vx1 && vy1) ? wx1 * wy1 : 0.0f;
    int xa = max(x0, 0);  // x0=-1 -> rec 0 holds (px0,px1); v10 in slot 0
    bool lo1 = x0 < 0;
    float wA0 = lo1 ? w10 : w00, wB0 = lo1 ? 0.0f : w10;
    float wA1 = lo1 ? w11 : w01, wB1 = lo1 ? 0.0f : w11;
    int y0c = min(max(y0, 0), HH - 1), y1c = min(max(y0 + 1, 0), HH - 1);
    off0 = y0c * 64 + xa;
    off1 = y1c * 64 + xa;
    hw0 = f2h2(wA0, wB0);
    hw1 = f2h2(wA1, wB1);
}

__device__ __forceinline__ void dot_s(uint2 q0, uint2 q1, h2 hw0, h2 hw1,
                                      float& acc0, float& acc1) {
    union { h2 h; uint32_t u; } w0, w1;
    w0.h = hw0;
    w1.h = hw1;
    acc0 = fdot2f(q0.x, hw0, acc0);
    acc1 = fdot2f(q0.y, hw0, acc1);
    acc0 = fdot2f(q1.x, hw1, acc0);
    acc1 = fdot2f(q1.y, hw1, acc1);
}

__device__ __forceinline__ void step_one(const uint2* __restrict__ recs,
                                         float axv, float ayv, float ckx,
                                         float cky, float& acc0, float& acc1) {
    int o0, o1;
    h2 w0, w1;
    prep_s(axv, ayv, ckx, cky, o0, o1, w0, w1);
    uint2 q0 = recs[o0], q1 = recs[o1];
    dot_s(q0, q1, w0, w1, acc0, acc1);
}

// ---------------------------------------------------------------------------
// Main kernel: thread = (cg, b, tl, y, x). Branch-free two-loop structure:
//   loop A: k in [0, t_lo], pairs of k, lo+hi samples (8 gathers batched);
//   loop B: k in (t_lo, t_hi], quads of k, hi only (8 gathers batched).
// All loads of a body are issued before any dot2 consumes them -> ~8
// gathers in flight per thread (vs ~2 with the guarded loop).
// ---------------------------------------------------------------------------
__global__ __launch_bounds__(256, 8) void warp_pscan_v11(
    const float* __restrict__ cum, const uint32_t* __restrict__ planes,
    float* __restrict__ out) {
    int idx = blockIdx.x * 256 + threadIdx.x;  // over 4*2*16*4096 = 524288
    if (idx >= 4 * BB * (LL / 2) * HWL) return;
    int x  = idx & (WW - 1);
    int y  = (idx >> 6) & (HH - 1);
    int tl = (idx >> 12) & 15;
    int b  = (idx >> 16) & 1;
    int cg = (idx >> 17) & 3;
    int t_lo = tl, t_hi = (LL - 1) - tl;
    int pix = y * WW + x;

    float gx = -1.0f + (float)(2 * x + 1) * (1.0f / WW);
    float gy = -1.0f + (float)(2 * y + 1) * (1.0f / HH);

    const float* cumb = cum + (size_t)b * LL * 2 * HWL + pix;
    float ctxlo = cumb[(size_t)(2 * t_lo) * HWL];
    float ctylo = cumb[(size_t)(2 * t_lo + 1) * HWL];
    float ctxhi = cumb[(size_t)(2 * t_hi) * HWL];
    float ctyhi = cumb[(size_t)(2 * t_hi + 1) * HWL];

    // Hoisted per-thread constants: a = (gx+1)+ctx - ckx  (±1ulp vs r10).
    float gx1 = gx + 1.0f, gy1 = gy + 1.0f;
    float axl = gx1 + ctxlo, ayl = gy1 + ctylo;
    float axh = gx1 + ctxhi, ayh = gy1 + ctyhi;

    float a0l = 0.0f, a1l = 0.0f, a0h = 0.0f, a1h = 0.0f;

    const uint2* plb =
        reinterpret_cast<const uint2*>(planes) + (size_t)(b * LL * 4 + cg) * 4096;
    const size_t KSTRIDE = 4 * 4096;  // uint2 per k-step

    int k = 0;
    // ---- Loop A: k-pairs, both t_lo and t_hi accumulate -------------------
    for (; k + 1 <= t_lo; k += 2) {
        float ckx0 = cumb[(size_t)(2 * k) * HWL];
        float cky0 = cumb[(size_t)(2 * k + 1) * HWL];
        float ckx1 = cumb[(size_t)(2 * k + 2) * HWL];
        float cky1 = cumb[(size_t)(2 * k + 3) * HWL];
        const uint2* r0 = plb + (size_t)k * KSTRIDE;
        const uint2* r1 = r0 + KSTRIDE;
        int ho00, ho01, lo00, lo01, ho10, ho11, lo10, lo11;
        h2 hw00, hw01, lw00, lw01, hw10, hw11, lw10, lw11;
        prep_s(axh, ayh, ckx0, cky0, ho00, ho01, hw00, hw01);
        prep_s(axl, ayl, ckx0, cky0, lo00, lo01, lw00, lw01);
        prep_s(axh, ayh, ckx1, cky1, ho10, ho11, hw10, hw11);
        prep_s(axl, ayl, ckx1, cky1, lo10, lo11, lw10, lw11);
        uint2 qh00 = r0[ho00], qh01 = r0[ho01];
        uint2 ql00 = r0[lo00], ql01 = r0[lo01];
        uint2 qh10 = r1[ho10], qh11 = r1[ho11];
        uint2 ql10 = r1[lo10], ql11 = r1[lo11];
        dot_s(qh00, qh01, hw00, hw01, a0h, a1h);
        dot_s(ql00, ql01, lw00, lw01, a0l, a1l);
        dot_s(qh10, qh11, hw10, hw11, a0h, a1h);
        dot_s(ql10, ql11, lw10, lw11, a0l, a1l);
    }
    if (k <= t_lo) {  // loop-A tail (single k, both samples)
        float ckx0 = cumb[(size_t)(2 * k) * HWL];
        float cky0 = cumb[(size_t)(2 * k + 1) * HWL];
        const uint2* r0 = plb + (size_t)k * KSTRIDE;
        int ho0, ho1, lo0, lo1;
        h2 hw0, hw1, lw0, lw1;
        prep_s(axh, ayh, ckx0, cky0, ho0, ho1, hw0, hw1);
        prep_s(axl, ayl, ckx0, cky0, lo0, lo1, lw0, lw1);
        uint2 qh0 = r0[ho0], qh1 = r0[ho1];
        uint2 ql0 = r0[lo0], ql1 = r0[lo1];
        dot_s(qh0, qh1, hw0, hw1, a0h, a1h);
        dot_s(ql0, ql1, lw0, lw1, a0l, a1l);
        ++k;
    }
    // ---- Loop B: k-quads, hi only -----------------------------------------
    for (; k + 3 <= t_hi; k += 4) {
        float cx0 = cumb[(size_t)(2 * k) * HWL];
        float cy0 = cumb[(size_t)(2 * k + 1) * HWL];
        float cx1 = cumb[(size_t)(2 * k + 2) * HWL];
        float cy1 = cumb[(size_t)(2 * k + 3) * HWL];
        float cx2 = cumb[(size_t)(2 * k + 4) * HWL];
        float cy2 = cumb[(size_t)(2 * k + 5) * HWL];
        float cx3 = cumb[(size_t)(2 * k + 6) * HWL];
        float cy3 = cumb[(size_t)(2 * k + 7) * HWL];
        const uint2* r0 = plb + (size_t)k * KSTRIDE;
        const uint2* r1 = r0 + KSTRIDE;
        const uint2* r2 = r1 + KSTRIDE;
        const uint2* r3 = r2 + KSTRIDE;
        int o00, o01, o10, o11, o20, o21, o30, o31;
        h2 w00, w01, w10, w11, w20, w21, w30, w31;
        prep_s(axh, ayh, cx0, cy0, o00, o01, w00, w01);
        prep_s(axh, ayh, cx1, cy1, o10, o11, w10, w11);
        prep_s(axh, ayh, cx2, cy2, o20, o21, w20, w21);
        prep_s(axh, ayh, cx3, cy3, o30, o31, w30, w31);
        uint2 q00 = r0[o00], q01 = r0[o01];
        uint2 q10 = r1[o10], q11 = r1[o11];
        uint2 q20 = r2[o20], q21 = r2[o21];
        uint2 q30 = r3[o30], q31 = r3[o31];
        dot_s(q00, q01, w00, w01, a0h, a1h);
        dot_s(q10, q11, w10, w11, a0h, a1h);
        dot_s(q20, q21, w20, w21, a0h, a1h);
        dot_s(q30, q31, w30, w31, a0h, a1h);
    }
    for (; k <= t_hi; ++k) {  // loop-B tail (1-3 singles)
        float cx = cumb[(size_t)(2 * k) * HWL];
        float cy = cumb[(size_t)(2 * k + 1) * HWL];
        step_one(plb + (size_t)k * KSTRIDE, axh, ayh, cx, cy, a0h, a1h);
    }

    int c0 = cg * 2;
    float* ol = out + ((size_t)(b * LL + t_lo) * CC + c0) * HWL + pix;
    ol[0]   = a0l;
    ol[HWL] = a1l;
    float* oh = out + ((size_t)(b * LL + t_hi) * CC + c0) * HWL + pix;
    oh[0]   = a0h;
    oh[HWL] = a1h;
}

// ---------------------------------------------------------------------------
// Fallback (ws too small): fp32 scalar path, original layouts (r5-proven).
// ---------------------------------------------------------------------------
__global__ __launch_bounds__(256) void warp_pscan_fb(
    const float* __restrict__ cum, const float* __restrict__ images,
    float* __restrict__ out) {
    int idx = blockIdx.x * blockDim.x + threadIdx.x;
    if (idx >= BB * LL * HWL) return;
    int x  = idx & (WW - 1);
    int y  = (idx >> 6) & (HH - 1);
    int tl = (idx >> 12) & (LL - 1);
    int b  = idx >> 17;
    int t = (tl < 16) ? tl : (47 - tl);
    int pix = y * WW + x;
    float gx = -1.0f + (float)(2 * x + 1) * (1.0f / WW);
    float gy = -1.0f + (float)(2 * y + 1) * (1.0f / HH);
    const float* cumb = cum + (size_t)b * LL * 2 * HWL + pix;
    float ctx = cumb[(size_t)(2 * t) * HWL];
    float cty = cumb[(size_t)(2 * t + 1) * HWL];
    float acc[CC];
#pragma unroll
    for (int c = 0; c < CC; ++c) acc[c] = 0.0f;
    const float* imgb = images + (size_t)b * LL * CC * HWL;
    for (int k = 0; k <= t; ++k) {
        float dx = ctx - cumb[(size_t)(2 * k) * HWL];
        float dy = cty - cumb[(size_t)(2 * k + 1) * HWL];
        float g0 = gx + dx, g1 = gy + dy;
        float a = g0 + 1.0f, h = a * 0.5f;
        float rem = (h - floorf(h)) * 2.0f;
        float ix = fmaf(rem, 32.0f, -0.5f);
        float iy = fmaf(g1 + 1.0f, 32.0f, -0.5f);
        float x0f = floorf(ix), y0f = floorf(iy);
        float wx1 = ix - x0f, wy1 = iy - y0f;
        float wx0 = 1.0f - wx1, wy0 = 1.0f - wy1;
        int x0 = (int)x0f, y0 = (int)y0f;
        bool vx0 = x0 >= 0, vx1 = x0 < WW - 1;
        bool vy0 = (y0 >= 0) & (y0 < HH), vy1 = (y0 >= -1) & (y0 < HH - 1);
        int x0c = max(x0, 0), x1c = min(x0 + 1, WW - 1);
        int y0c = min(max(y0, 0), HH - 1), y1c = min(max(y0 + 1, 0), HH - 1);
        float w00 = (vx0 && vy0) ? wx0 * wy0 : 0.0f;
        float w10 = (vx1 && vy0) ? wx1 * wy0 : 0.0f;
        float w01 = (vx0 && vy1) ? wx0 * wy1 : 0.0f;
        float w11 = (vx1 && vy1) ? wx1 * wy1 : 0.0f;
        int o00 = y0c * WW + x0c, o10 = y0c * WW + x1c;
        int o01 = y1c * WW + x0c, o11 = y1c * WW + x1c;
        const float* ip = imgb + (size_t)k * CC * HWL;
#pragma unroll
        for (int c = 0; c < CC; ++c) {
            const float* ic = ip + (size_t)c * HWL;
            acc[c] += w00 * ic[o00] + w10 * ic[o10] + w01 * ic[o01] +
                      w11 * ic[o11];
        }
    }
    float* op = out + ((size_t)(b * LL + t) * CC) * HWL + pix;
#pragma unroll
    for (int c = 0; c < CC; ++c) op[(size_t)c * HWL] = acc[c];
}

extern "C" void kernel_launch(void* const* d_in, const int* in_sizes, int n_in,
                              void* d_out, int out_size, void* d_ws,
                              size_t ws_size, hipStream_t stream) {
    const float* flows  = (const float*)d_in[0];
    const float* images = (const float*)d_in[1];
    float* out = (float*)d_out;

    const size_t cum_bytes   = (size_t)BB * LL * 2 * HWL * sizeof(float);  // 2 MiB
    const size_t plane_bytes = (size_t)BB * LL * 4 * 4096 * 8;             // 8 MiB
    float* cum       = (float*)d_ws;
    uint32_t* planes = (uint32_t*)((char*)d_ws + cum_bytes);
    bool full = (ws_size >= cum_bytes + plane_bytes);

    if (full) {
        int nprep = CUM_BLOCKS + (BB * LL * HH * 32) / 256;  // 64 + 512 = 576
        prep_kernel<<<nprep, 256, 0, stream>>>(flows, images, cum, planes);
        int n3 = 4 * BB * (LL / 2) * HWL;  // 524288
        warp_pscan_v11<<<n3 / 256, 256, 0, stream>>>(cum, planes, out);
    } else {
        prep_kernel<<<CUM_BLOCKS, 256, 0, stream>>>(flows, images, cum,
                                                    planes);
        int n3 = BB * LL * HWL;
        warp_pscan_fb<<<(n3 + 255) / 256, 256, 0, stream>>>(cum, images, out);
    }
}